// Round 1
// baseline (296.405 us; speedup 1.0000x reference)
//
#include <hip/hip_runtime.h>
#include <hip/hip_bf16.h>

// Problem constants (match reference)
#define BB 8
#define NN 4096
#define MM 4096
#define DD 128

typedef float  f32x4 __attribute__((ext_vector_type(4)));
typedef _Float16 f16x8 __attribute__((ext_vector_type(8)));
typedef _Float16 f16x2 __attribute__((ext_vector_type(2)));

__device__ __forceinline__ void async_copy16(const void* g, void* l) {
    __builtin_amdgcn_global_load_lds(
        (const __attribute__((address_space(1))) void*)g,
        (__attribute__((address_space(3))) void*)l, 16, 0, 0);
}

// Convert fp32 rows (D=128) to f16 and compute exact fp32 squared row norms.
// One wave per row; lane handles 2 elements.
__global__ void prep_kernel(const float* __restrict__ src,
                            _Float16* __restrict__ dst,
                            float* __restrict__ sq, int rows) {
    int wave = (int)((blockIdx.x * blockDim.x + threadIdx.x) >> 6);
    int lane = threadIdx.x & 63;
    if (wave >= rows) return;
    const float2 v = ((const float2*)src)[(size_t)wave * 64 + lane];
    float s = v.x * v.x + v.y * v.y;
    f16x2 h;
    h.x = (_Float16)v.x;
    h.y = (_Float16)v.y;
    ((f16x2*)dst)[(size_t)wave * 64 + lane] = h;
    #pragma unroll
    for (int off = 32; off; off >>= 1) s += __shfl_down(s, off, 64);
    if (lane == 0) sq[wave] = s;
}

__global__ void init_kernel(unsigned int* __restrict__ fwd, float* __restrict__ bsum) {
    int i = blockIdx.x * blockDim.x + threadIdx.x;
    if (i < BB * MM) fwd[i] = 0x7f800000u;  // +inf bits
    if (i == 0) *bsum = 0.0f;
}

// Main fused kernel: per block a 128(n) x 128(m) tile, loop over all 8 batches.
// xy via MFMA f16; dist epilogue updates forward (atomicMin per (b,m)) and a
// register-resident backward min-over-b, summed at the end.
__global__ __launch_bounds__(256, 2)
void chamfer_main(const _Float16* __restrict__ xh, const _Float16* __restrict__ yh,
                  const float* __restrict__ x2, const float* __restrict__ y2,
                  unsigned int* __restrict__ fwd, float* __restrict__ bsum) {
    __shared__ _Float16 xs[128 * 128];  // 32 KB
    __shared__ _Float16 ys[128 * 128];  // 32 KB

    const int tid  = threadIdx.x;
    const int lane = tid & 63;
    const int wave = tid >> 6;
    const int wr   = wave >> 1;      // wave row (0..1) -> 64 rows each
    const int wc   = wave & 1;       // wave col (0..1) -> 64 cols each
    const int quad = lane >> 4;
    const int l15  = lane & 15;
    const int n0   = blockIdx.x * 128;
    const int m0   = blockIdx.y * 128;

    const float INF = __builtin_inff();

    f32x4 bmin[4][4];
    #pragma unroll
    for (int i = 0; i < 4; ++i)
        #pragma unroll
        for (int j = 0; j < 4; ++j)
            bmin[i][j] = (f32x4){INF, INF, INF, INF};

    for (int b = 0; b < BB; ++b) {
        // ---- stage: both tiles are contiguous 32KB blocks in global ----
        const char* xg = (const char*)(xh + ((size_t)b * NN + n0) * DD);
        const char* yg = (const char*)(yh + ((size_t)b * MM + m0) * DD);
        #pragma unroll
        for (int r = 0; r < 8; ++r) {
            int off = r * 4096 + wave * 1024 + lane * 16;
            async_copy16(xg + off, (char*)xs + off);
        }
        #pragma unroll
        for (int r = 0; r < 8; ++r) {
            int off = r * 4096 + wave * 1024 + lane * 16;
            async_copy16(yg + off, (char*)ys + off);
        }
        __syncthreads();  // drains vmcnt -> LDS tiles complete

        // ---- MFMA: acc[fi][fj] = x_tile . y_tile^T  (64x64 per wave) ----
        f32x4 acc[4][4];
        #pragma unroll
        for (int i = 0; i < 4; ++i)
            #pragma unroll
            for (int j = 0; j < 4; ++j)
                acc[i][j] = (f32x4){0.f, 0.f, 0.f, 0.f};

        #pragma unroll
        for (int kk = 0; kk < DD; kk += 32) {
            f16x8 a[4], bf[4];
            #pragma unroll
            for (int fi = 0; fi < 4; ++fi)
                a[fi] = *(const f16x8*)&xs[(wr * 64 + fi * 16 + l15) * DD + kk + quad * 8];
            #pragma unroll
            for (int fj = 0; fj < 4; ++fj)
                bf[fj] = *(const f16x8*)&ys[(wc * 64 + fj * 16 + l15) * DD + kk + quad * 8];
            #pragma unroll
            for (int fi = 0; fi < 4; ++fi)
                #pragma unroll
                for (int fj = 0; fj < 4; ++fj)
                    acc[fi][fj] = __builtin_amdgcn_mfma_f32_16x16x32_f16(
                        a[fi], bf[fj], acc[fi][fj], 0, 0, 0);
        }

        // ---- epilogue: dist + forward/backward mins ----
        const float* x2b = x2 + (size_t)b * NN + n0;
        const float* y2b = y2 + (size_t)b * MM + m0;
        float y2v[4];
        #pragma unroll
        for (int fj = 0; fj < 4; ++fj)
            y2v[fj] = y2b[wc * 64 + fj * 16 + l15];

        float fwd_min[4] = {INF, INF, INF, INF};
        #pragma unroll
        for (int fi = 0; fi < 4; ++fi) {
            // rows for this fragment: wr*64 + fi*16 + quad*4 + e  (16B aligned)
            const f32x4 x2v = *(const f32x4*)(x2b + wr * 64 + fi * 16 + quad * 4);
            #pragma unroll
            for (int fj = 0; fj < 4; ++fj) {
                #pragma unroll
                for (int e = 0; e < 4; ++e) {
                    float sq = x2v[e] + y2v[fj] - 2.0f * acc[fi][fj][e];
                    float d  = sqrtf(fmaxf(sq, 0.0f));
                    bmin[fi][fj][e] = fminf(bmin[fi][fj][e], d);
                    fwd_min[fj]     = fminf(fwd_min[fj], d);
                }
            }
        }
        // forward: reduce min over the 4 quads (rows), then atomicMin per col
        #pragma unroll
        for (int fj = 0; fj < 4; ++fj) {
            float v = fwd_min[fj];
            v = fminf(v, __shfl_xor(v, 16, 64));
            v = fminf(v, __shfl_xor(v, 32, 64));
            if (quad == 0) {
                int m = m0 + wc * 64 + fj * 16 + l15;
                atomicMin(&fwd[(size_t)b * MM + m], __float_as_uint(v));
            }
        }
        __syncthreads();  // protect LDS before next batch's staging
    }

    // backward: sum of min-over-b over this block's tile
    float s = 0.0f;
    #pragma unroll
    for (int fi = 0; fi < 4; ++fi)
        #pragma unroll
        for (int fj = 0; fj < 4; ++fj)
            #pragma unroll
            for (int e = 0; e < 4; ++e)
                s += bmin[fi][fj][e];
    #pragma unroll
    for (int off = 32; off; off >>= 1) s += __shfl_down(s, off, 64);
    if (lane == 0) atomicAdd(bsum, s);
}

__global__ void finalize_kernel(const float* __restrict__ fwd,
                                const float* __restrict__ bsum,
                                float* __restrict__ out) {
    __shared__ float partial[4];
    int tid = threadIdx.x;
    int lane = tid & 63;
    int wave = tid >> 6;
    float s = 0.0f;
    for (int i = tid; i < BB * MM; i += 256) s += fwd[i];
    #pragma unroll
    for (int off = 32; off; off >>= 1) s += __shfl_down(s, off, 64);
    if (lane == 0) partial[wave] = s;
    __syncthreads();
    if (tid == 0) {
        float fs = partial[0] + partial[1] + partial[2] + partial[3];
        out[0] = fs / (float)(BB * MM) + bsum[0] / ((float)NN * (float)MM);
    }
}

extern "C" void kernel_launch(void* const* d_in, const int* in_sizes, int n_in,
                              void* d_out, int out_size, void* d_ws, size_t ws_size,
                              hipStream_t stream) {
    const float* x = (const float*)d_in[0];  // (B,N,D)
    const float* y = (const float*)d_in[1];  // (B,M,D)
    float* out = (float*)d_out;

    char* w = (char*)d_ws;
    _Float16* xh = (_Float16*)(w);                         // 8 MB
    _Float16* yh = (_Float16*)(w + 8388608);               // 8 MB
    float*    x2 = (float*)(w + 16777216);                 // 128 KB
    float*    y2 = (float*)(w + 16908288);                 // 128 KB
    unsigned int* fwd = (unsigned int*)(w + 17039360);     // 128 KB
    float*    bsum = (float*)(w + 17170432);               // 4 B

    // prep: one wave per row, 4 waves per block
    prep_kernel<<<(BB * NN) / 4, 256, 0, stream>>>(x, xh, x2, BB * NN);
    prep_kernel<<<(BB * MM) / 4, 256, 0, stream>>>(y, yh, y2, BB * MM);
    init_kernel<<<(BB * MM + 255) / 256, 256, 0, stream>>>(fwd, bsum);

    dim3 grid(NN / 128, MM / 128);
    chamfer_main<<<grid, 256, 0, stream>>>(xh, yh, x2, y2, fwd, bsum);

    finalize_kernel<<<1, 256, 0, stream>>>((const float*)fwd, bsum, out);
}

// Round 2
// 248.769 us; speedup vs baseline: 1.1915x; 1.1915x over previous
//
#include <hip/hip_runtime.h>
#include <hip/hip_bf16.h>

#define BB 8
#define NN 4096
#define MM 4096
#define DD 128

typedef float  f32x4 __attribute__((ext_vector_type(4)));
typedef _Float16 f16x8 __attribute__((ext_vector_type(8)));
typedef _Float16 f16x2 __attribute__((ext_vector_type(2)));

__device__ __forceinline__ void async_copy16(const void* g, void* l) {
    __builtin_amdgcn_global_load_lds(
        (const __attribute__((address_space(1))) void*)g,
        (__attribute__((address_space(3))) void*)l, 16, 0, 0);
}

// Fused prep: fp32->f16 convert + exact fp32 squared row norms for BOTH
// inputs, plus init of fwd/bsum/counter. One wave per row (2 floats/lane).
__global__ void prep_all(const float* __restrict__ x, const float* __restrict__ y,
                         _Float16* __restrict__ xh, _Float16* __restrict__ yh,
                         float* __restrict__ x2, float* __restrict__ y2,
                         unsigned int* __restrict__ fwd, float* __restrict__ bsum,
                         unsigned int* __restrict__ counter) {
    int gtid = blockIdx.x * blockDim.x + threadIdx.x;
    // init section (fwd is only 32768 entries; grid has 4.1M threads)
    if (gtid < BB * MM) fwd[gtid] = 0x7f800000u;  // +inf bits
    if (gtid == 0) { *bsum = 0.0f; *counter = 0u; }

    int wv   = gtid >> 6;
    int lane = threadIdx.x & 63;
    const float* src;
    _Float16* dst;
    float* sq;
    int row;
    if (wv < BB * NN) {
        src = x; dst = xh; sq = x2; row = wv;
    } else {
        src = y; dst = yh; sq = y2; row = wv - BB * NN;
    }
    const float2 v = ((const float2*)src)[(size_t)row * 64 + lane];
    float s = v.x * v.x + v.y * v.y;
    f16x2 h;
    h.x = (_Float16)v.x;
    h.y = (_Float16)v.y;
    ((f16x2*)dst)[(size_t)row * 64 + lane] = h;
    #pragma unroll
    for (int off = 32; off; off >>= 1) s += __shfl_down(s, off, 64);
    if (lane == 0) sq[row] = s;
}

// Main fused kernel. 128(n) x 128(m) tile per block, loop b=0..7.
// LDS layout XOR-swizzled: LDS(row, chunk c') holds global chunk c'^(row&15).
// Swizzle applied on the global SOURCE address during global_load_lds staging
// (LDS dest must stay base+lane*16), and on the chunk index at ds_read_b128.
__global__ __launch_bounds__(256, 2)
void chamfer_main(const _Float16* __restrict__ xh, const _Float16* __restrict__ yh,
                  const float* __restrict__ x2, const float* __restrict__ y2,
                  unsigned int* __restrict__ fwd, float* __restrict__ bsum,
                  unsigned int* __restrict__ counter, float* __restrict__ out) {
    __shared__ _Float16 xs[128 * 128];  // 32 KB
    __shared__ _Float16 ys[128 * 128];  // 32 KB

    const int tid  = threadIdx.x;
    const int lane = tid & 63;
    const int wave = tid >> 6;
    const int wr   = wave >> 1;
    const int wc   = wave & 1;
    const int quad = lane >> 4;
    const int l15  = lane & 15;
    const int n0   = blockIdx.x * 128;
    const int m0   = blockIdx.y * 128;

    // staging address precompute (constant across r and b):
    // dest LDS off = r*4096 + wave*1024 + lane*16  (natural, lane-contiguous)
    // row = r*16 + wave*4 + (lane>>4); row&15 = wave*4 + (lane>>4)
    // source chunk = (lane&15) ^ (row&15)
    const int l4 = lane >> 4;
    const int swchunk = (lane & 15) ^ ((wave << 2) | l4);
    const int src_base = wave * 1024 + l4 * 256 + swchunk * 16;
    const int dst_base = wave * 1024 + lane * 16;

    const float INF = __builtin_inff();

    f32x4 bmin[4][4];
    #pragma unroll
    for (int i = 0; i < 4; ++i)
        #pragma unroll
        for (int j = 0; j < 4; ++j)
            bmin[i][j] = (f32x4){INF, INF, INF, INF};

    for (int b = 0; b < BB; ++b) {
        const char* xg = (const char*)(xh + ((size_t)b * NN + n0) * DD);
        const char* yg = (const char*)(yh + ((size_t)b * MM + m0) * DD);
        #pragma unroll
        for (int r = 0; r < 8; ++r)
            async_copy16(xg + r * 4096 + src_base, (char*)xs + r * 4096 + dst_base);
        #pragma unroll
        for (int r = 0; r < 8; ++r)
            async_copy16(yg + r * 4096 + src_base, (char*)ys + r * 4096 + dst_base);
        __syncthreads();

        f32x4 acc[4][4];
        #pragma unroll
        for (int i = 0; i < 4; ++i)
            #pragma unroll
            for (int j = 0; j < 4; ++j)
                acc[i][j] = (f32x4){0.f, 0.f, 0.f, 0.f};

        #pragma unroll
        for (int kk = 0; kk < DD; kk += 32) {
            const int cb = kk >> 3;  // 0,4,8,12 ; logical chunk = cb|quad
            const int sw = ((cb | quad) ^ l15) << 3;  // swizzled f16 offset in row
            f16x8 a[4], bf[4];
            #pragma unroll
            for (int fi = 0; fi < 4; ++fi)
                a[fi] = *(const f16x8*)&xs[(wr * 64 + fi * 16 + l15) * DD + sw];
            #pragma unroll
            for (int fj = 0; fj < 4; ++fj)
                bf[fj] = *(const f16x8*)&ys[(wc * 64 + fj * 16 + l15) * DD + sw];
            #pragma unroll
            for (int fi = 0; fi < 4; ++fi)
                #pragma unroll
                for (int fj = 0; fj < 4; ++fj)
                    acc[fi][fj] = __builtin_amdgcn_mfma_f32_16x16x32_f16(
                        a[fi], bf[fj], acc[fi][fj], 0, 0, 0);
        }

        // epilogue on SQUARED distances (sqrt/clamp deferred; min is monotone)
        const float* x2b = x2 + (size_t)b * NN + n0;
        const float* y2b = y2 + (size_t)b * MM + m0;
        float y2v[4];
        #pragma unroll
        for (int fj = 0; fj < 4; ++fj)
            y2v[fj] = y2b[wc * 64 + fj * 16 + l15];

        float fwd_min[4] = {INF, INF, INF, INF};
        #pragma unroll
        for (int fi = 0; fi < 4; ++fi) {
            const f32x4 x2v = *(const f32x4*)(x2b + wr * 64 + fi * 16 + quad * 4);
            #pragma unroll
            for (int fj = 0; fj < 4; ++fj) {
                #pragma unroll
                for (int e = 0; e < 4; ++e) {
                    float sqv = fmaf(-2.0f, acc[fi][fj][e], x2v[e] + y2v[fj]);
                    bmin[fi][fj][e] = fminf(bmin[fi][fj][e], sqv);
                    fwd_min[fj]     = fminf(fwd_min[fj], sqv);
                }
            }
        }
        #pragma unroll
        for (int fj = 0; fj < 4; ++fj) {
            float v = fwd_min[fj];
            v = fminf(v, __shfl_xor(v, 16, 64));
            v = fminf(v, __shfl_xor(v, 32, 64));
            v = fmaxf(v, 0.0f);  // clamp so uint ordering == float ordering
            if (quad == 0) {
                int m = m0 + wc * 64 + fj * 16 + l15;
                atomicMin(&fwd[(size_t)b * MM + m], __float_as_uint(v));
            }
        }
        __syncthreads();
    }

    // backward: sqrt(clamp(min-over-b)) once per element, sum, one atomic/wave
    float s = 0.0f;
    #pragma unroll
    for (int fi = 0; fi < 4; ++fi)
        #pragma unroll
        for (int fj = 0; fj < 4; ++fj)
            #pragma unroll
            for (int e = 0; e < 4; ++e)
                s += sqrtf(fmaxf(bmin[fi][fj][e], 0.0f));
    #pragma unroll
    for (int off = 32; off; off >>= 1) s += __shfl_down(s, off, 64);
    if (lane == 0) atomicAdd(bsum, s);

    // fused finalize: last block to finish reduces fwd + combines means
    __shared__ float red[4];
    __shared__ int isLast;
    __threadfence();
    if (tid == 0) {
        unsigned int c = atomicAdd(counter, 1u);
        isLast = (c == gridDim.x * gridDim.y - 1) ? 1 : 0;
    }
    __syncthreads();
    if (isLast) {
        float fs = 0.0f;
        for (int i = tid; i < BB * MM; i += 256) {
            unsigned int u = __hip_atomic_load(&fwd[i], __ATOMIC_RELAXED,
                                               __HIP_MEMORY_SCOPE_AGENT);
            fs += sqrtf(__uint_as_float(u));
        }
        #pragma unroll
        for (int off = 32; off; off >>= 1) fs += __shfl_down(fs, off, 64);
        if (lane == 0) red[wave] = fs;
        __syncthreads();
        if (tid == 0) {
            float ftot = red[0] + red[1] + red[2] + red[3];
            float bs = __hip_atomic_load(bsum, __ATOMIC_RELAXED,
                                         __HIP_MEMORY_SCOPE_AGENT);
            out[0] = ftot / (float)(BB * MM) + bs / ((float)NN * (float)MM);
        }
    }
}

extern "C" void kernel_launch(void* const* d_in, const int* in_sizes, int n_in,
                              void* d_out, int out_size, void* d_ws, size_t ws_size,
                              hipStream_t stream) {
    const float* x = (const float*)d_in[0];  // (B,N,D)
    const float* y = (const float*)d_in[1];  // (B,M,D)
    float* out = (float*)d_out;

    char* w = (char*)d_ws;
    _Float16* xh = (_Float16*)(w);                         // 8 MB
    _Float16* yh = (_Float16*)(w + 8388608);               // 8 MB
    float*    x2 = (float*)(w + 16777216);                 // 128 KB
    float*    y2 = (float*)(w + 16908288);                 // 128 KB
    unsigned int* fwd = (unsigned int*)(w + 17039360);     // 128 KB
    float*    bsum = (float*)(w + 17170432);               // 4 B
    unsigned int* counter = (unsigned int*)(w + 17170436); // 4 B

    // 2*32768 rows, one wave each, 4 waves/block
    prep_all<<<(2 * BB * NN) / 4, 256, 0, stream>>>(x, y, xh, yh, x2, y2,
                                                    fwd, bsum, counter);
    dim3 grid(NN / 128, MM / 128);
    chamfer_main<<<grid, 256, 0, stream>>>(xh, yh, x2, y2, fwd, bsum, counter, out);
}